// Round 7
// baseline (442.334 us; speedup 1.0000x reference)
//
#include <hip/hip_runtime.h>
#include <hip/hip_bf16.h>

// Problem constants
#define NPAT 4096   // patches
#define EDIM 64     // embedding per head
#define NH   8      // heads
#define HE   512    // H*E
#define OUTD 64     // CIN*P^3

typedef short bf16x8 __attribute__((ext_vector_type(8)));
typedef float f32x4  __attribute__((ext_vector_type(4)));

#if __has_builtin(__builtin_amdgcn_exp2f)
#define EXP2(x) __builtin_amdgcn_exp2f(x)
#else
#define EXP2(x) exp2f(x)
#endif

__device__ __forceinline__ ushort f2bf(float f) {
    uint u = __builtin_bit_cast(uint, f);
    return (ushort)((u + 0x7FFFu + ((u >> 16) & 1u)) >> 16);
}
__device__ __forceinline__ float bf2f(ushort b) {
    return __builtin_bit_cast(float, ((uint)b) << 16);
}

// ---------------- Kernel 1: conv3d(stride4) + LN + pos -> emb fp32 [4096][64]
__global__ __launch_bounds__(64) void k_embed(
    const float* __restrict__ voxel,   // [64][64][64]
    const float* __restrict__ conv_w,  // [64][64]
    const float* __restrict__ conv_b,  // [64]
    const float* __restrict__ ln_g, const float* __restrict__ ln_b,
    const float* __restrict__ pos,     // [4096][64]
    float* __restrict__ emb)           // [4096][64]
{
    const int n = blockIdx.x;
    const int d = n >> 8, hh = (n >> 4) & 15, ww = n & 15;
    const int t = threadIdx.x;  // 0..63 (one wave)
    __shared__ float vox[64];
    __shared__ float wsm[64 * 65];  // padded stride 65 to spread banks

    for (int i = t; i < 4096; i += 64) wsm[(i >> 6) * 65 + (i & 63)] = conv_w[i];
    const int i3 = t >> 4, j3 = (t >> 2) & 3, k3 = t & 3;
    vox[t] = voxel[(d * 4 + i3) * 4096 + (hh * 4 + j3) * 64 + (ww * 4 + k3)];
    __syncthreads();

    float acc = conv_b[t];
    #pragma unroll
    for (int m = 0; m < 64; m++) acc += vox[m] * wsm[t * 65 + m];

    // LayerNorm across the 64 lanes (one wave)
    float s1 = acc, s2 = acc * acc;
    #pragma unroll
    for (int off = 1; off < 64; off <<= 1) {
        s1 += __shfl_xor(s1, off);
        s2 += __shfl_xor(s2, off);
    }
    const float mu  = s1 * (1.0f / 64.0f);
    const float var = s2 * (1.0f / 64.0f) - mu * mu;
    const float y = (acc - mu) * rsqrtf(var + 1e-5f) * ln_g[t] + ln_b[t] + pos[n * 64 + t];
    emb[n * 64 + t] = y;
}

// ---------------- Kernel 2: projections -> qk bf16 [H][N][64], vT bf16 [H][64][N]
__global__ __launch_bounds__(256) void k_proj(
    const float* __restrict__ emb,   // [4096][64]
    const float* __restrict__ wqk, const float* __restrict__ bqk,
    const float* __restrict__ wv,  const float* __restrict__ bvv,
    ushort* __restrict__ qk_bf,      // [H][4096][64]
    ushort* __restrict__ vT_bf)      // [H][64][4096]
{
    const int n0 = blockIdx.x * 16;
    const int t = threadIdx.x;  // 0..255
    __shared__ float es[16][64];
    for (int i = t; i < 16 * 64; i += 256) es[i >> 6][i & 63] = emb[n0 * 64 + i];
    __syncthreads();

    const int he0 = t, he1 = t + 256;
    const float bq0 = bqk[he0], bq1 = bqk[he1];
    const float bv0 = bvv[he0], bv1 = bvv[he1];

    for (int rc = 0; rc < 2; rc++) {
        float aq0[8], aq1[8], av0[8], av1[8];
        #pragma unroll
        for (int r = 0; r < 8; r++) { aq0[r] = bq0; aq1[r] = bq1; av0[r] = bv0; av1[r] = bv1; }
        for (int e = 0; e < 64; e++) {
            const float wq0 = wqk[e * HE + he0], wq1 = wqk[e * HE + he1];
            const float wv0 = wv [e * HE + he0], wv1 = wv [e * HE + he1];
            #pragma unroll
            for (int r = 0; r < 8; r++) {
                const float x = es[rc * 8 + r][e];
                aq0[r] += x * wq0; aq1[r] += x * wq1;
                av0[r] += x * wv0; av1[r] += x * wv1;
            }
        }
        #pragma unroll
        for (int r = 0; r < 8; r++) {
            const int n = n0 + rc * 8 + r;
            qk_bf[((he0 >> 6) * NPAT + n) * 64 + (he0 & 63)] = f2bf(aq0[r]);
            qk_bf[((he1 >> 6) * NPAT + n) * 64 + (he1 & 63)] = f2bf(aq1[r]);
            vT_bf[((he0 >> 6) * 64 + (he0 & 63)) * NPAT + n] = f2bf(av0[r]);
            vT_bf[((he1 >> 6) * 64 + (he1 & 63)) * NPAT + n] = f2bf(av1[r]);
        }
    }
}

// ---------------- Kernel 2b: q2[h][n] = sum_e qk^2
__global__ __launch_bounds__(256) void k_q2(
    const ushort* __restrict__ qk_bf, float* __restrict__ q2)
{
    const int i = blockIdx.x * 256 + threadIdx.x;  // 0..32767 = h*4096+n
    const ushort* row = qk_bf + (size_t)i * 64;
    float s = 0.0f;
    #pragma unroll
    for (int c = 0; c < 8; c++) {
        bf16x8 v = *(const bf16x8*)(row + c * 8);
        #pragma unroll
        for (int j = 0; j < 8; j++) { float f = bf2f((ushort)v[j]); s += f * f; }
    }
    q2[i] = s;
}

// ---------------- Kernel 3: fused L2-distance attention
// 1024 threads = 16 waves = 4 row-groups (rg) x 4 KV-splits (s). Each wave:
// 16 rows x 1024 KV cols. Partial O (acc) and Z (zacc) combined across the 4
// s-waves through LDS at the end (scores bounded -> plain partial sums, no
// running-max rescale). Raises waves/SIMD from 2 to 8 (grid was the occupancy
// limiter at 23.5%).
// p_lds is per-wave private: cross-lane write->read pinned by wave_barrier
// (0 instructions); in-order DS pipe gives HW ordering within the wave.
__global__ __launch_bounds__(1024, 8) void k_attn(
    const ushort* __restrict__ qk,   // [H][N][64] bf16
    const ushort* __restrict__ vT,   // [H][64][N] bf16
    const float* __restrict__ q2,    // [H][N]
    const float* __restrict__ alpha, // [1]
    float* __restrict__ attn)        // [N][512]
{
    const int h  = blockIdx.y;
    const int bx = blockIdx.x;          // 64-row tile
    const int tid = threadIdx.x;
    const int w  = tid >> 6;            // wave 0..15
    const int s  = w >> 2;              // KV split 0..3
    const int rg = w & 3;               // row group 0..3
    const int l  = tid & 63;
    const int lr = l & 15;
    const int lg = l >> 4;
    const float L2E = 1.4426950408889634f;
    const float ccl2e = alpha[0] * 0.125f * L2E;

    __shared__ ushort p_lds[16][16 * 64];  // per-wave P tile, XOR-swizzled (32 KB)
    __shared__ f32x4 cbuf[12][64];         // cross-split combine staging (12 KB)

    const ushort* qkh = qk + (size_t)h * NPAT * 64;
    const ushort* vTh = vT + (size_t)h * 64 * NPAT;
    const float*  q2h = q2 + h * NPAT;

    const int row0 = bx * 64 + rg * 16;

    // Q A-fragments: row = row0+lr, k = 32f + 8*lg + j
    bf16x8 aq0, aq1;
    {
        const ushort* qrow = qkh + (size_t)(row0 + lr) * 64 + 8 * lg;
        aq0 = *(const bf16x8*)(qrow);
        aq1 = *(const bf16x8*)(qrow + 32);
    }
    float nq2[4];
    #pragma unroll
    for (int r = 0; r < 4; r++) nq2[r] = q2h[row0 + 4 * lg + r];

    f32x4 acc[4];
    #pragma unroll
    for (int c = 0; c < 4; c++) acc[c] = (f32x4){0.f, 0.f, 0.f, 0.f};
    float zacc[4] = {0.f, 0.f, 0.f, 0.f};

    char* pbase = (char*)(&p_lds[w][0]);

    const int j_beg = s * (NPAT / 4), j_end = (s + 1) * (NPAT / 4);
    for (int j0 = j_beg; j0 < j_end; j0 += 64) {
        // ---- QK^T for 4 col-tiles, p, stash P in LDS
        #pragma unroll
        for (int t = 0; t < 4; t++) {
            const ushort* krow = qkh + (size_t)(j0 + t * 16 + lr) * 64 + 8 * lg;
            bf16x8 bk0 = *(const bf16x8*)(krow);
            bf16x8 bk1 = *(const bf16x8*)(krow + 32);
            f32x4 sc = (f32x4){0.f, 0.f, 0.f, 0.f};
            sc = __builtin_amdgcn_mfma_f32_16x16x32_bf16(aq0, bk0, sc, 0, 0, 0);
            sc = __builtin_amdgcn_mfma_f32_16x16x32_bf16(aq1, bk1, sc, 0, 0, 0);
            const float k2c = q2h[j0 + t * 16 + lr];
            #pragma unroll
            for (int r = 0; r < 4; r++) {
                const float d = nq2[r] + k2c - 2.0f * sc[r];
                const float p = EXP2(ccl2e * EXP2(-L2E * d));
                zacc[r] += p;
                const int row = 4 * lg + r, col = 16 * t + lr;
                const int byteoff = row * 128 + ((col * 2) ^ ((row & 7) << 4));
                *(ushort*)(pbase + byteoff) = f2bf(p);
            }
        }
        // pin compiler ordering: all P writes before the cross-lane read-back
        __builtin_amdgcn_wave_barrier();
        // ---- read P back as A-fragments (row = lr, k-chunk = 32f + 8*lg)
        bf16x8 pa0, pa1;
        {
            char* rb = pbase + lr * 128;
            const int x = (lr & 7) << 4;
            pa0 = *(const bf16x8*)(rb + ((16 * lg) ^ x));
            pa1 = *(const bf16x8*)(rb + ((64 + 16 * lg) ^ x));
        }
        // pin ordering: reads complete (in DS pipe order) before next iter's writes
        __builtin_amdgcn_wave_barrier();
        // ---- PV: O[c-tile] += P * V
        #pragma unroll
        for (int c = 0; c < 4; c++) {
            const ushort* vrow = vTh + (size_t)(c * 16 + lr) * NPAT + j0 + 8 * lg;
            bf16x8 bv0 = *(const bf16x8*)(vrow);
            bf16x8 bv1 = *(const bf16x8*)(vrow + 32);
            acc[c] = __builtin_amdgcn_mfma_f32_16x16x32_bf16(pa0, bv0, acc[c], 0, 0, 0);
            acc[c] = __builtin_amdgcn_mfma_f32_16x16x32_bf16(pa1, bv1, acc[c], 0, 0, 0);
        }
    }

    // ---- combine partial O and Z across the 4 KV-split waves (same rg).
    // 5 rounds through a 12 KB buffer; static indices only (no runtime acc[c]).
#define COMBINE(V)                                         \
    do {                                                   \
        if (s > 0) cbuf[(s - 1) * 4 + rg][l] = (V);        \
        __syncthreads();                                   \
        if (s == 0) {                                      \
            (V) += cbuf[0 * 4 + rg][l];                    \
            (V) += cbuf[1 * 4 + rg][l];                    \
            (V) += cbuf[2 * 4 + rg][l];                    \
        }                                                  \
        __syncthreads();                                   \
    } while (0)

    COMBINE(acc[0]);
    COMBINE(acc[1]);
    COMBINE(acc[2]);
    COMBINE(acc[3]);
    f32x4 zv = (f32x4){zacc[0], zacc[1], zacc[2], zacc[3]};
    COMBINE(zv);
#undef COMBINE

    if (s == 0) {
        // reduce Z across the 16 col-lanes of each group, normalize, store
        float zinv[4];
        #pragma unroll
        for (int r = 0; r < 4; r++) {
            float z = zv[r];
            z += __shfl_xor(z, 1); z += __shfl_xor(z, 2);
            z += __shfl_xor(z, 4); z += __shfl_xor(z, 8);
            zinv[r] = 1.0f / z;
        }
        #pragma unroll
        for (int c = 0; c < 4; c++) {
            #pragma unroll
            for (int r = 0; r < 4; r++) {
                const int row = row0 + 4 * lg + r;
                attn[(size_t)row * HE + h * 64 + c * 16 + lr] = acc[c][r] * zinv[r];
            }
        }
    }
}

// ---------------- Kernel 4: out = attn @ wout + bout
__global__ __launch_bounds__(256) void k_out(
    const float* __restrict__ attn,  // [4096][512]
    const float* __restrict__ wout,  // [512][64]
    const float* __restrict__ bout,  // [64]
    float* __restrict__ out)         // [4096][64]
{
    const int n0 = blockIdx.x * 16;
    const int t = threadIdx.x;
    const int c = t & 63, rg = t >> 6;
    __shared__ float sa[16][512];
    for (int i = t; i < 16 * 512; i += 256) sa[i >> 9][i & 511] = attn[(size_t)n0 * 512 + i];
    __syncthreads();
    #pragma unroll
    for (int rr = 0; rr < 4; rr++) {
        const int r = rg * 4 + rr;
        float acc = bout[c];
        for (int k = 0; k < 512; k++) acc += sa[r][k] * wout[k * 64 + c];
        out[(size_t)(n0 + r) * 64 + c] = acc;
    }
}

extern "C" void kernel_launch(void* const* d_in, const int* in_sizes, int n_in,
                              void* d_out, int out_size, void* d_ws, size_t ws_size,
                              hipStream_t stream) {
    (void)in_sizes; (void)n_in; (void)out_size; (void)ws_size;
    const float* voxel  = (const float*)d_in[0];
    const float* conv_w = (const float*)d_in[1];
    const float* conv_b = (const float*)d_in[2];
    const float* ln_g   = (const float*)d_in[3];
    const float* ln_b   = (const float*)d_in[4];
    const float* pos    = (const float*)d_in[5];
    const float* wqk    = (const float*)d_in[6];
    const float* bqk    = (const float*)d_in[7];
    const float* wv     = (const float*)d_in[8];
    const float* bvv    = (const float*)d_in[9];
    const float* alpha  = (const float*)d_in[10];
    const float* wout   = (const float*)d_in[11];
    const float* bout   = (const float*)d_in[12];
    float* out = (float*)d_out;

    char* ws = (char*)d_ws;
    float*  emb   = (float*) (ws);                                   // 1 MB
    ushort* qk_bf = (ushort*)(ws + (1u << 20));                      // 4 MB
    ushort* vT_bf = (ushort*)(ws + 5u * (1u << 20));                 // 4 MB
    float*  q2    = (float*) (ws + 9u * (1u << 20));                 // 128 KB
    float*  attn  = (float*) (ws + 9u * (1u << 20) + (128u << 10));  // 8 MB

    k_embed<<<NPAT, 64, 0, stream>>>(voxel, conv_w, conv_b, ln_g, ln_b, pos, emb);
    k_proj<<<NPAT / 16, 256, 0, stream>>>(emb, wqk, bqk, wv, bvv, qk_bf, vT_bf);
    k_q2<<<(NH * NPAT) / 256, 256, 0, stream>>>(qk_bf, q2);
    k_attn<<<dim3(NPAT / 64, NH), 1024, 0, stream>>>(qk_bf, vT_bf, q2, alpha, attn);
    k_out<<<NPAT / 16, 256, 0, stream>>>(attn, wout, bout, out);
}

// Round 8
// 226.134 us; speedup vs baseline: 1.9561x; 1.9561x over previous
//
#include <hip/hip_runtime.h>
#include <hip/hip_bf16.h>

// Problem constants
#define NPAT 4096   // patches
#define EDIM 64     // embedding per head
#define NH   8      // heads
#define HE   512    // H*E
#define OUTD 64     // CIN*P^3

typedef short bf16x8 __attribute__((ext_vector_type(8)));
typedef float f32x4  __attribute__((ext_vector_type(4)));

#if __has_builtin(__builtin_amdgcn_exp2f)
#define EXP2(x) __builtin_amdgcn_exp2f(x)
#else
#define EXP2(x) exp2f(x)
#endif

__device__ __forceinline__ ushort f2bf(float f) {
    uint u = __builtin_bit_cast(uint, f);
    return (ushort)((u + 0x7FFFu + ((u >> 16) & 1u)) >> 16);
}
__device__ __forceinline__ float bf2f(ushort b) {
    return __builtin_bit_cast(float, ((uint)b) << 16);
}

// ---------------- Kernel 1: conv3d(stride4) + LN + pos -> emb fp32 [4096][64]
__global__ __launch_bounds__(64) void k_embed(
    const float* __restrict__ voxel,   // [64][64][64]
    const float* __restrict__ conv_w,  // [64][64]
    const float* __restrict__ conv_b,  // [64]
    const float* __restrict__ ln_g, const float* __restrict__ ln_b,
    const float* __restrict__ pos,     // [4096][64]
    float* __restrict__ emb)           // [4096][64]
{
    const int n = blockIdx.x;
    const int d = n >> 8, hh = (n >> 4) & 15, ww = n & 15;
    const int t = threadIdx.x;  // 0..63 (one wave)
    __shared__ float vox[64];
    __shared__ float wsm[64 * 65];  // padded stride 65 to spread banks

    for (int i = t; i < 4096; i += 64) wsm[(i >> 6) * 65 + (i & 63)] = conv_w[i];
    const int i3 = t >> 4, j3 = (t >> 2) & 3, k3 = t & 3;
    vox[t] = voxel[(d * 4 + i3) * 4096 + (hh * 4 + j3) * 64 + (ww * 4 + k3)];
    __syncthreads();

    float acc = conv_b[t];
    #pragma unroll
    for (int m = 0; m < 64; m++) acc += vox[m] * wsm[t * 65 + m];

    // LayerNorm across the 64 lanes (one wave)
    float s1 = acc, s2 = acc * acc;
    #pragma unroll
    for (int off = 1; off < 64; off <<= 1) {
        s1 += __shfl_xor(s1, off);
        s2 += __shfl_xor(s2, off);
    }
    const float mu  = s1 * (1.0f / 64.0f);
    const float var = s2 * (1.0f / 64.0f) - mu * mu;
    const float y = (acc - mu) * rsqrtf(var + 1e-5f) * ln_g[t] + ln_b[t] + pos[n * 64 + t];
    emb[n * 64 + t] = y;
}

// ---------------- Kernel 2: projections -> qk bf16 [H][N][64], vT bf16 [H][64][N]
__global__ __launch_bounds__(256) void k_proj(
    const float* __restrict__ emb,   // [4096][64]
    const float* __restrict__ wqk, const float* __restrict__ bqk,
    const float* __restrict__ wv,  const float* __restrict__ bvv,
    ushort* __restrict__ qk_bf,      // [H][4096][64]
    ushort* __restrict__ vT_bf)      // [H][64][4096]
{
    const int n0 = blockIdx.x * 16;
    const int t = threadIdx.x;  // 0..255
    __shared__ float es[16][64];
    for (int i = t; i < 16 * 64; i += 256) es[i >> 6][i & 63] = emb[n0 * 64 + i];
    __syncthreads();

    const int he0 = t, he1 = t + 256;
    const float bq0 = bqk[he0], bq1 = bqk[he1];
    const float bv0 = bvv[he0], bv1 = bvv[he1];

    for (int rc = 0; rc < 2; rc++) {
        float aq0[8], aq1[8], av0[8], av1[8];
        #pragma unroll
        for (int r = 0; r < 8; r++) { aq0[r] = bq0; aq1[r] = bq1; av0[r] = bv0; av1[r] = bv1; }
        for (int e = 0; e < 64; e++) {
            const float wq0 = wqk[e * HE + he0], wq1 = wqk[e * HE + he1];
            const float wv0 = wv [e * HE + he0], wv1 = wv [e * HE + he1];
            #pragma unroll
            for (int r = 0; r < 8; r++) {
                const float x = es[rc * 8 + r][e];
                aq0[r] += x * wq0; aq1[r] += x * wq1;
                av0[r] += x * wv0; av1[r] += x * wv1;
            }
        }
        #pragma unroll
        for (int r = 0; r < 8; r++) {
            const int n = n0 + rc * 8 + r;
            qk_bf[((he0 >> 6) * NPAT + n) * 64 + (he0 & 63)] = f2bf(aq0[r]);
            qk_bf[((he1 >> 6) * NPAT + n) * 64 + (he1 & 63)] = f2bf(aq1[r]);
            vT_bf[((he0 >> 6) * 64 + (he0 & 63)) * NPAT + n] = f2bf(av0[r]);
            vT_bf[((he1 >> 6) * 64 + (he1 & 63)) * NPAT + n] = f2bf(av1[r]);
        }
    }
}

// ---------------- Kernel 2b: q2[h][n] = sum_e qk^2
__global__ __launch_bounds__(256) void k_q2(
    const ushort* __restrict__ qk_bf, float* __restrict__ q2)
{
    const int i = blockIdx.x * 256 + threadIdx.x;  // 0..32767 = h*4096+n
    const ushort* row = qk_bf + (size_t)i * 64;
    float s = 0.0f;
    #pragma unroll
    for (int c = 0; c < 8; c++) {
        bf16x8 v = *(const bf16x8*)(row + c * 8);
        #pragma unroll
        for (int j = 0; j < 8; j++) { float f = bf2f((ushort)v[j]); s += f * f; }
    }
    q2[i] = s;
}

// ---------------- Kernel 3: fused L2-distance attention, LDS-staged KV stream
// Block: 64 Q-rows x head h; 16 waves = 4 row-groups (rg) x 4 col-roles (u).
// Per KV-tile (64 cols): all 1024 threads cooperatively stage K-tile (8 KB) and
// V-tile (8 KB) via global_load_lds (linear LDS dest; global source chunk
// pre-swizzled with XOR(row&7) so ds_read_b128 is bank-spread). Wave (rg,u):
// QK^T sub-tile t=u -> P (exp(cc*exp(-d))) into shared p_lds[rg]; then PV
// c-tile c=u. Barrier B is lgkmcnt-only (raw s_barrier) so the next-tile
// prefetch stays in flight across it; __syncthreads at loop top drains it.
// Grid: 1D 512, h = bid&7 -> all 64 blocks of a head on one XCD (L2 reuse).
__global__ __launch_bounds__(1024, 8) void k_attn(
    const ushort* __restrict__ qk,   // [H][N][64] bf16
    const ushort* __restrict__ vT,   // [H][64][N] bf16
    const float* __restrict__ q2,    // [H][N]
    const float* __restrict__ alpha, // [1]
    float* __restrict__ attn)        // [N][512]
{
    const int bid = blockIdx.x;
    const int h  = bid & 7;
    const int bx = bid >> 3;
    const int tid = threadIdx.x;
    const int w  = tid >> 6;            // wave 0..15
    const int u  = w & 3;               // col-role (t-subtile for QK, c-tile for PV)
    const int rg = w >> 2;              // row group 0..3
    const int l  = tid & 63;
    const int lr = l & 15;
    const int lg = l >> 4;
    const float L2E = 1.4426950408889634f;
    const float ccl2e = alpha[0] * 0.125f * L2E;

    __shared__ ushort kv_lds[2][2][64 * 64]; // [buf][0=K,1=V][row*64+elem] 32 KB
    __shared__ ushort p_lds[4][16 * 64];     // per-rg P tile, XOR-swizzled (8 KB)
    __shared__ float  zpart[4][4][16];       // z stripe-sums [rg][u][row] (1 KB)

    const ushort* qkh = qk + (size_t)h * NPAT * 64;
    const ushort* vTh = vT + (size_t)h * 64 * NPAT;
    const float*  q2h = q2 + h * NPAT;

    const int row0 = bx * 64 + rg * 16;

    // Q A-fragments: row = row0+lr, k = 32f + 8*lg + j
    bf16x8 aq0, aq1;
    {
        const ushort* qrow = qkh + (size_t)(row0 + lr) * 64 + 8 * lg;
        aq0 = *(const bf16x8*)(qrow);
        aq1 = *(const bf16x8*)(qrow + 32);
    }
    float nq2[4];
    #pragma unroll
    for (int r = 0; r < 4; r++) nq2[r] = q2h[row0 + 4 * lg + r];

    // staging role: waves 0-7 stage K rows, 8-15 stage V rows (8 rows/wave)
    const int w8   = w & 7;
    const int srow = w8 * 8 + (l >> 3);          // 0..63
    const int sch  = (l & 7) ^ (srow & 7);       // inverse-swizzled source chunk
    const ushort* ksrc0 = qkh + (size_t)srow * 64 + sch * 8;   // + it*4096
    const ushort* vsrc0 = vTh + (size_t)srow * NPAT + sch * 8; // + it*64
    // wave-uniform LDS dest base: HW writes lane l at base + l*16 B
#define STAGE(bufi, it)                                                          \
    do {                                                                         \
        const ushort* _src = (w < 8) ? (ksrc0 + (size_t)(it) * 4096)             \
                                     : (vsrc0 + (size_t)(it) * 64);              \
        ushort* _dst = &kv_lds[bufi][w >> 3][w8 * 512];                          \
        __builtin_amdgcn_global_load_lds(                                        \
            (const __attribute__((address_space(1))) unsigned int*)_src,         \
            (__attribute__((address_space(3))) unsigned int*)_dst, 16, 0, 0);    \
    } while (0)

    f32x4 acc = (f32x4){0.f, 0.f, 0.f, 0.f};
    float zacc[4] = {0.f, 0.f, 0.f, 0.f};

    const int x7 = (lr & 7);             // swizzle key (row&7 == lr&7 for our rows)
    char* prg = (char*)&p_lds[rg][0];

    STAGE(0, 0);  // prologue
    float k2c = q2h[u * 16 + lr];

    for (int it = 0; it < 64; ++it) {
        const int buf = it & 1;
        __syncthreads();  // A: drains vmcnt (staging of buf complete), prev reads retired
        if (it + 1 < 64) STAGE(buf ^ 1, it + 1);       // prefetch flies over barrier B
        float k2n = (it + 1 < 64) ? q2h[(it + 1) * 64 + u * 16 + lr] : 0.f;

        // ---- QK^T sub-tile t=u: rows row0.., K-rows it*64 + 16u..
        {
            const ushort* kb = &kv_lds[buf][0][0];
            const int krow = u * 16 + lr;
            bf16x8 bk0 = *(const bf16x8*)(kb + krow * 64 + ((lg ^ x7) << 3));
            bf16x8 bk1 = *(const bf16x8*)(kb + krow * 64 + (((lg + 4) ^ x7) << 3));
            f32x4 sc = (f32x4){0.f, 0.f, 0.f, 0.f};
            sc = __builtin_amdgcn_mfma_f32_16x16x32_bf16(aq0, bk0, sc, 0, 0, 0);
            sc = __builtin_amdgcn_mfma_f32_16x16x32_bf16(aq1, bk1, sc, 0, 0, 0);
            #pragma unroll
            for (int r = 0; r < 4; r++) {
                const float d = nq2[r] + k2c - 2.0f * sc[r];
                const float p = EXP2(ccl2e * EXP2(-L2E * d));
                zacc[r] += p;
                const int prow = 4 * lg + r, pcol = 16 * u + lr;
                const int byteoff = prow * 128 + ((pcol * 2) ^ ((prow & 7) << 4));
                *(ushort*)(prg + byteoff) = f2bf(p);
            }
        }
        // B: P visible to the rg's 4 waves; lgkmcnt-only so prefetch stays in flight
        asm volatile("s_waitcnt lgkmcnt(0)" ::: "memory");
        __builtin_amdgcn_s_barrier();

        // ---- PV c-tile c=u: O[rows][e=16u+lr] += P * V
        {
            const ushort* vb = &kv_lds[buf][1][0];
            const int vrow = u * 16 + lr;  // e-index
            bf16x8 bv0 = *(const bf16x8*)(vb + vrow * 64 + ((lg ^ x7) << 3));
            bf16x8 bv1 = *(const bf16x8*)(vb + vrow * 64 + (((lg + 4) ^ x7) << 3));
            char* rb = prg + lr * 128;
            const int xx = x7 << 4;
            bf16x8 pa0 = *(const bf16x8*)(rb + ((16 * lg) ^ xx));
            bf16x8 pa1 = *(const bf16x8*)(rb + ((64 + 16 * lg) ^ xx));
            acc = __builtin_amdgcn_mfma_f32_16x16x32_bf16(pa0, bv0, acc, 0, 0, 0);
            acc = __builtin_amdgcn_mfma_f32_16x16x32_bf16(pa1, bv1, acc, 0, 0, 0);
        }
        k2c = k2n;
    }
#undef STAGE

    // ---- Z: stripe sums (cols 16u+..) -> LDS -> total row sums -> normalize
    #pragma unroll
    for (int r = 0; r < 4; r++) {
        float z = zacc[r];
        z += __shfl_xor(z, 1); z += __shfl_xor(z, 2);
        z += __shfl_xor(z, 4); z += __shfl_xor(z, 8);
        if (lr == 0) zpart[rg][u][4 * lg + r] = z;
    }
    __syncthreads();
    #pragma unroll
    for (int r = 0; r < 4; r++) {
        const int row = 4 * lg + r;
        const float zt = zpart[rg][0][row] + zpart[rg][1][row] +
                         zpart[rg][2][row] + zpart[rg][3][row];
        attn[(size_t)(row0 + row) * HE + h * 64 + u * 16 + lr] = acc[r] / zt;
    }
}

// ---------------- Kernel 4: out = attn @ wout + bout
__global__ __launch_bounds__(256) void k_out(
    const float* __restrict__ attn,  // [4096][512]
    const float* __restrict__ wout,  // [512][64]
    const float* __restrict__ bout,  // [64]
    float* __restrict__ out)         // [4096][64]
{
    const int n0 = blockIdx.x * 16;
    const int t = threadIdx.x;
    const int c = t & 63, rg = t >> 6;
    __shared__ float sa[16][512];
    for (int i = t; i < 16 * 512; i += 256) sa[i >> 9][i & 511] = attn[(size_t)n0 * 512 + i];
    __syncthreads();
    #pragma unroll
    for (int rr = 0; rr < 4; rr++) {
        const int r = rg * 4 + rr;
        float acc = bout[c];
        for (int k = 0; k < 512; k++) acc += sa[r][k] * wout[k * 64 + c];
        out[(size_t)(n0 + r) * 64 + c] = acc;
    }
}

extern "C" void kernel_launch(void* const* d_in, const int* in_sizes, int n_in,
                              void* d_out, int out_size, void* d_ws, size_t ws_size,
                              hipStream_t stream) {
    (void)in_sizes; (void)n_in; (void)out_size; (void)ws_size;
    const float* voxel  = (const float*)d_in[0];
    const float* conv_w = (const float*)d_in[1];
    const float* conv_b = (const float*)d_in[2];
    const float* ln_g   = (const float*)d_in[3];
    const float* ln_b   = (const float*)d_in[4];
    const float* pos    = (const float*)d_in[5];
    const float* wqk    = (const float*)d_in[6];
    const float* bqk    = (const float*)d_in[7];
    const float* wv     = (const float*)d_in[8];
    const float* bvv    = (const float*)d_in[9];
    const float* alpha  = (const float*)d_in[10];
    const float* wout   = (const float*)d_in[11];
    const float* bout   = (const float*)d_in[12];
    float* out = (float*)d_out;

    char* ws = (char*)d_ws;
    float*  emb   = (float*) (ws);                                   // 1 MB
    ushort* qk_bf = (ushort*)(ws + (1u << 20));                      // 4 MB
    ushort* vT_bf = (ushort*)(ws + 5u * (1u << 20));                 // 4 MB
    float*  q2    = (float*) (ws + 9u * (1u << 20));                 // 128 KB
    float*  attn  = (float*) (ws + 9u * (1u << 20) + (128u << 10));  // 8 MB

    k_embed<<<NPAT, 64, 0, stream>>>(voxel, conv_w, conv_b, ln_g, ln_b, pos, emb);
    k_proj<<<NPAT / 16, 256, 0, stream>>>(emb, wqk, bqk, wv, bvv, qk_bf, vT_bf);
    k_q2<<<(NH * NPAT) / 256, 256, 0, stream>>>(qk_bf, q2);
    k_attn<<<NPAT / 64 * NH, 1024, 0, stream>>>(qk_bf, vT_bf, q2, alpha, attn);
    k_out<<<NPAT / 16, 256, 0, stream>>>(attn, wout, bout, out);
}

// Round 10
// 203.893 us; speedup vs baseline: 2.1694x; 1.1091x over previous
//
#include <hip/hip_runtime.h>
#include <hip/hip_bf16.h>

// Problem constants
#define NPAT 4096   // patches
#define EDIM 64     // embedding per head
#define NH   8      // heads
#define HE   512    // H*E
#define OUTD 64     // CIN*P^3

typedef short bf16x8 __attribute__((ext_vector_type(8)));
typedef float f32x4  __attribute__((ext_vector_type(4)));

#if __has_builtin(__builtin_amdgcn_exp2f)
#define EXP2(x) __builtin_amdgcn_exp2f(x)
#else
#define EXP2(x) exp2f(x)
#endif

__device__ __forceinline__ ushort f2bf(float f) {
    uint u = __builtin_bit_cast(uint, f);
    return (ushort)((u + 0x7FFFu + ((u >> 16) & 1u)) >> 16);
}
__device__ __forceinline__ float bf2f(ushort b) {
    return __builtin_bit_cast(float, ((uint)b) << 16);
}

// ---------------- Kernel 1 v2: conv3d(stride4)+LN+pos -> emb fp32 [4096][64]
// 256 blocks x 256 thr; block b = (d,hh), 16 patches (ww). conv_w staged ONCE
// per block (was: once per patch = 66 MB L2 traffic). Voxel read coalesced via
// float4: for fixed (i,j), (ww,k) spans 64 consecutive floats.
__global__ __launch_bounds__(256) void k_embed(
    const float* __restrict__ voxel,   // [64][64][64]
    const float* __restrict__ conv_w,  // [64][64]
    const float* __restrict__ conv_b,  // [64]
    const float* __restrict__ ln_g, const float* __restrict__ ln_b,
    const float* __restrict__ pos,     // [4096][64]
    float* __restrict__ emb)           // [4096][64]
{
    const int b = blockIdx.x;          // d*16 + hh
    const int d = b >> 4, hh = b & 15;
    const int t = threadIdx.x;         // 0..255
    __shared__ float wsm[64][65];      // conv_w padded (16.6 KB)
    __shared__ float vox[16][64];      // [i*4+j][ww*4+k] (4 KB)

    for (int i = t; i < 4096; i += 256) wsm[i >> 6][i & 63] = conv_w[i];
    {
        const int pair = t >> 4;                 // i*4+j
        const int off4 = (t & 15) * 4;           // ww*4+k chunk
        const float4 v = *(const float4*)&voxel[(d * 4 + (pair >> 2)) * 4096 +
                                                (hh * 4 + (pair & 3)) * 64 + off4];
        *(float4*)&vox[pair][off4] = v;
    }
    __syncthreads();

    const int wv = t >> 6;             // wave 0..3
    const int l  = t & 63;
    const int p  = wv * 4 + (l >> 4);  // patch ww 0..15
    const int eb = l & 15;             // e = eb + 16*o
    const int n  = b * 16 + p;

    float acc[4];
    #pragma unroll
    for (int o = 0; o < 4; o++) acc[o] = conv_b[eb + 16 * o];
    for (int m = 0; m < 64; m++) {
        const float v = vox[m >> 2][p * 4 + (m & 3)];
        #pragma unroll
        for (int o = 0; o < 4; o++) acc[o] += v * wsm[eb + 16 * o][m];
    }

    // LayerNorm over the 64 e (16 lanes x 4 outputs)
    float s1 = acc[0] + acc[1] + acc[2] + acc[3];
    float s2 = acc[0] * acc[0] + acc[1] * acc[1] + acc[2] * acc[2] + acc[3] * acc[3];
    #pragma unroll
    for (int off = 1; off < 16; off <<= 1) {
        s1 += __shfl_xor(s1, off);
        s2 += __shfl_xor(s2, off);
    }
    const float mu  = s1 * (1.0f / 64.0f);
    const float var = s2 * (1.0f / 64.0f) - mu * mu;
    const float rs  = rsqrtf(var + 1e-5f);
    #pragma unroll
    for (int o = 0; o < 4; o++) {
        const int e = eb + 16 * o;
        emb[n * 64 + e] = (acc[o] - mu) * rs * ln_g[e] + ln_b[e] + pos[n * 64 + e];
    }
}

// ---------------- Kernel 1b: woutT bf16 [64][512] (transpose+convert, tiny)
__global__ __launch_bounds__(256) void k_wt(
    const float* __restrict__ wout,  // [512][64]
    ushort* __restrict__ woutT)      // [64][512]
{
    const int b = blockIdx.x;        // 8 blocks, k-slab of 64
    const int t = threadIdx.x;
    __shared__ float ld[64][65];
    for (int i = t; i < 4096; i += 256) ld[i >> 6][i & 63] = wout[(b * 64 + (i >> 6)) * 64 + (i & 63)];
    __syncthreads();
    const int o = t >> 2, kb = (t & 3) * 16;
    #pragma unroll
    for (int j = 0; j < 16; j++)
        woutT[o * 512 + b * 64 + kb + j] = f2bf(ld[kb + j][o]);
}

// ---------------- Kernel 2: projections -> qk bf16 [H][N][64], vT bf16 [H][64][N]
__global__ __launch_bounds__(256) void k_proj(
    const float* __restrict__ emb,   // [4096][64]
    const float* __restrict__ wqk, const float* __restrict__ bqk,
    const float* __restrict__ wv,  const float* __restrict__ bvv,
    ushort* __restrict__ qk_bf,      // [H][4096][64]
    ushort* __restrict__ vT_bf)      // [H][64][4096]
{
    const int n0 = blockIdx.x * 16;
    const int t = threadIdx.x;  // 0..255
    __shared__ float es[16][64];
    for (int i = t; i < 16 * 64; i += 256) es[i >> 6][i & 63] = emb[n0 * 64 + i];
    __syncthreads();

    const int he0 = t, he1 = t + 256;
    const float bq0 = bqk[he0], bq1 = bqk[he1];
    const float bv0 = bvv[he0], bv1 = bvv[he1];

    for (int rc = 0; rc < 2; rc++) {
        float aq0[8], aq1[8], av0[8], av1[8];
        #pragma unroll
        for (int r = 0; r < 8; r++) { aq0[r] = bq0; aq1[r] = bq1; av0[r] = bv0; av1[r] = bv1; }
        for (int e = 0; e < 64; e++) {
            const float wq0 = wqk[e * HE + he0], wq1 = wqk[e * HE + he1];
            const float wv0 = wv [e * HE + he0], wv1 = wv [e * HE + he1];
            #pragma unroll
            for (int r = 0; r < 8; r++) {
                const float x = es[rc * 8 + r][e];
                aq0[r] += x * wq0; aq1[r] += x * wq1;
                av0[r] += x * wv0; av1[r] += x * wv1;
            }
        }
        #pragma unroll
        for (int r = 0; r < 8; r++) {
            const int n = n0 + rc * 8 + r;
            qk_bf[((he0 >> 6) * NPAT + n) * 64 + (he0 & 63)] = f2bf(aq0[r]);
            qk_bf[((he1 >> 6) * NPAT + n) * 64 + (he1 & 63)] = f2bf(aq1[r]);
            vT_bf[((he0 >> 6) * 64 + (he0 & 63)) * NPAT + n] = f2bf(av0[r]);
            vT_bf[((he1 >> 6) * 64 + (he1 & 63)) * NPAT + n] = f2bf(av1[r]);
        }
    }
}

// ---------------- Kernel 2b: q2[h][n] = sum_e qk^2
__global__ __launch_bounds__(256) void k_q2(
    const ushort* __restrict__ qk_bf, float* __restrict__ q2)
{
    const int i = blockIdx.x * 256 + threadIdx.x;  // 0..32767 = h*4096+n
    const ushort* row = qk_bf + (size_t)i * 64;
    float s = 0.0f;
    #pragma unroll
    for (int c = 0; c < 8; c++) {
        bf16x8 v = *(const bf16x8*)(row + c * 8);
        #pragma unroll
        for (int j = 0; j < 8; j++) { float f = bf2f((ushort)v[j]); s += f * f; }
    }
    q2[i] = s;
}

// ---------------- Kernel 3: fused L2-distance attention, LDS-staged KV stream
// (structure unchanged from R8's verified kernel; epilogue now stores bf16)
__global__ __launch_bounds__(1024, 8) void k_attn(
    const ushort* __restrict__ qk,   // [H][N][64] bf16
    const ushort* __restrict__ vT,   // [H][64][N] bf16
    const float* __restrict__ q2,    // [H][N]
    const float* __restrict__ alpha, // [1]
    ushort* __restrict__ attn)       // [N][512] bf16
{
    const int bid = blockIdx.x;
    const int h  = bid & 7;
    const int bx = bid >> 3;
    const int tid = threadIdx.x;
    const int w  = tid >> 6;            // wave 0..15
    const int u  = w & 3;               // col-role (t-subtile for QK, c-tile for PV)
    const int rg = w >> 2;              // row group 0..3
    const int l  = tid & 63;
    const int lr = l & 15;
    const int lg = l >> 4;
    const float L2E = 1.4426950408889634f;
    const float ccl2e = alpha[0] * 0.125f * L2E;

    __shared__ ushort kv_lds[2][2][64 * 64]; // [buf][0=K,1=V][row*64+elem] 32 KB
    __shared__ ushort p_lds[4][16 * 64];     // per-rg P tile, XOR-swizzled (8 KB)
    __shared__ float  zpart[4][4][16];       // z stripe-sums [rg][u][row] (1 KB)

    const ushort* qkh = qk + (size_t)h * NPAT * 64;
    const ushort* vTh = vT + (size_t)h * 64 * NPAT;
    const float*  q2h = q2 + h * NPAT;

    const int row0 = bx * 64 + rg * 16;

    bf16x8 aq0, aq1;
    {
        const ushort* qrow = qkh + (size_t)(row0 + lr) * 64 + 8 * lg;
        aq0 = *(const bf16x8*)(qrow);
        aq1 = *(const bf16x8*)(qrow + 32);
    }
    float nq2[4];
    #pragma unroll
    for (int r = 0; r < 4; r++) nq2[r] = q2h[row0 + 4 * lg + r];

    const int w8   = w & 7;
    const int srow = w8 * 8 + (l >> 3);
    const int sch  = (l & 7) ^ (srow & 7);
    const ushort* ksrc0 = qkh + (size_t)srow * 64 + sch * 8;
    const ushort* vsrc0 = vTh + (size_t)srow * NPAT + sch * 8;
#define STAGE(bufi, it)                                                          \
    do {                                                                         \
        const ushort* _src = (w < 8) ? (ksrc0 + (size_t)(it) * 4096)             \
                                     : (vsrc0 + (size_t)(it) * 64);              \
        ushort* _dst = &kv_lds[bufi][w >> 3][w8 * 512];                          \
        __builtin_amdgcn_global_load_lds(                                        \
            (const __attribute__((address_space(1))) unsigned int*)_src,         \
            (__attribute__((address_space(3))) unsigned int*)_dst, 16, 0, 0);    \
    } while (0)

    f32x4 acc = (f32x4){0.f, 0.f, 0.f, 0.f};
    float zacc[4] = {0.f, 0.f, 0.f, 0.f};

    const int x7 = (lr & 7);
    char* prg = (char*)&p_lds[rg][0];

    STAGE(0, 0);
    float k2c = q2h[u * 16 + lr];

    for (int it = 0; it < 64; ++it) {
        const int buf = it & 1;
        __syncthreads();  // A: staging of buf complete, prev reads retired
        if (it + 1 < 64) STAGE(buf ^ 1, it + 1);
        float k2n = (it + 1 < 64) ? q2h[(it + 1) * 64 + u * 16 + lr] : 0.f;

        {
            const ushort* kb = &kv_lds[buf][0][0];
            const int krow = u * 16 + lr;
            bf16x8 bk0 = *(const bf16x8*)(kb + krow * 64 + ((lg ^ x7) << 3));
            bf16x8 bk1 = *(const bf16x8*)(kb + krow * 64 + (((lg + 4) ^ x7) << 3));
            f32x4 sc = (f32x4){0.f, 0.f, 0.f, 0.f};
            sc = __builtin_amdgcn_mfma_f32_16x16x32_bf16(aq0, bk0, sc, 0, 0, 0);
            sc = __builtin_amdgcn_mfma_f32_16x16x32_bf16(aq1, bk1, sc, 0, 0, 0);
            #pragma unroll
            for (int r = 0; r < 4; r++) {
                const float d = nq2[r] + k2c - 2.0f * sc[r];
                const float p = EXP2(ccl2e * EXP2(-L2E * d));
                zacc[r] += p;
                const int prow = 4 * lg + r, pcol = 16 * u + lr;
                const int byteoff = prow * 128 + ((pcol * 2) ^ ((prow & 7) << 4));
                *(ushort*)(prg + byteoff) = f2bf(p);
            }
        }
        asm volatile("s_waitcnt lgkmcnt(0)" ::: "memory");
        __builtin_amdgcn_s_barrier();

        {
            const ushort* vb = &kv_lds[buf][1][0];
            const int vrow = u * 16 + lr;
            bf16x8 bv0 = *(const bf16x8*)(vb + vrow * 64 + ((lg ^ x7) << 3));
            bf16x8 bv1 = *(const bf16x8*)(vb + vrow * 64 + (((lg + 4) ^ x7) << 3));
            char* rb = prg + lr * 128;
            const int xx = x7 << 4;
            bf16x8 pa0 = *(const bf16x8*)(rb + ((16 * lg) ^ xx));
            bf16x8 pa1 = *(const bf16x8*)(rb + ((64 + 16 * lg) ^ xx));
            acc = __builtin_amdgcn_mfma_f32_16x16x32_bf16(pa0, bv0, acc, 0, 0, 0);
            acc = __builtin_amdgcn_mfma_f32_16x16x32_bf16(pa1, bv1, acc, 0, 0, 0);
        }
        k2c = k2n;
    }
#undef STAGE

    #pragma unroll
    for (int r = 0; r < 4; r++) {
        float z = zacc[r];
        z += __shfl_xor(z, 1); z += __shfl_xor(z, 2);
        z += __shfl_xor(z, 4); z += __shfl_xor(z, 8);
        if (lr == 0) zpart[rg][u][4 * lg + r] = z;
    }
    __syncthreads();
    #pragma unroll
    for (int r = 0; r < 4; r++) {
        const int row = 4 * lg + r;
        const float zt = zpart[rg][0][row] + zpart[rg][1][row] +
                         zpart[rg][2][row] + zpart[rg][3][row];
        attn[(size_t)(row0 + row) * HE + h * 64 + u * 16 + lr] = f2bf(acc[r] / zt);
    }
}

// ---------------- Kernel 4 v2: out = attn_bf @ woutT^T + bout via MFMA
// 256 blocks x 4 waves; block = 16 rows, wave w = 16 out-cols; K=512 -> 16 MFMA.
__global__ __launch_bounds__(256) void k_out(
    const ushort* __restrict__ attn,  // [4096][512] bf16
    const ushort* __restrict__ woutT, // [64][512] bf16
    const float* __restrict__ bout,   // [64]
    float* __restrict__ out)          // [4096][64]
{
    const int n0 = blockIdx.x * 16;
    const int t = threadIdx.x;
    const int w = t >> 6, l = t & 63, lr = l & 15, lg = l >> 4;
    __shared__ ushort sa[16][520];    // +8 pad: lanes lr spread 2-way only

    for (int c = t; c < 1024; c += 256) {
        const int row = c >> 6, c8 = c & 63;
        *(bf16x8*)&sa[row][c8 * 8] = *(const bf16x8*)&attn[(size_t)(n0 + row) * 512 + c8 * 8];
    }
    __syncthreads();

    f32x4 acc = (f32x4){0.f, 0.f, 0.f, 0.f};
    const ushort* bp = woutT + (size_t)(w * 16 + lr) * 512 + 8 * lg;
    #pragma unroll
    for (int kk = 0; kk < 16; kk++) {
        bf16x8 a = *(const bf16x8*)&sa[lr][kk * 32 + 8 * lg];
        bf16x8 bb = *(const bf16x8*)(bp + kk * 32);
        acc = __builtin_amdgcn_mfma_f32_16x16x32_bf16(a, bb, acc, 0, 0, 0);
    }
    const float bo = bout[w * 16 + lr];
    #pragma unroll
    for (int r = 0; r < 4; r++)
        out[(size_t)(n0 + 4 * lg + r) * 64 + w * 16 + lr] = acc[r] + bo;
}

extern "C" void kernel_launch(void* const* d_in, const int* in_sizes, int n_in,
                              void* d_out, int out_size, void* d_ws, size_t ws_size,
                              hipStream_t stream) {
    (void)in_sizes; (void)n_in; (void)out_size; (void)ws_size;
    const float* voxel  = (const float*)d_in[0];
    const float* conv_w = (const float*)d_in[1];
    const float* conv_b = (const float*)d_in[2];
    const float* ln_g   = (const float*)d_in[3];
    const float* ln_b   = (const float*)d_in[4];
    const float* pos    = (const float*)d_in[5];
    const float* wqk    = (const float*)d_in[6];
    const float* bqk    = (const float*)d_in[7];
    const float* wv     = (const float*)d_in[8];
    const float* bvv    = (const float*)d_in[9];
    const float* alpha  = (const float*)d_in[10];
    const float* wout   = (const float*)d_in[11];
    const float* bout   = (const float*)d_in[12];
    float* out = (float*)d_out;

    char* ws = (char*)d_ws;
    float*  emb     = (float*) (ws);                                   // 1 MB
    ushort* qk_bf   = (ushort*)(ws + (1u << 20));                      // 4 MB
    ushort* vT_bf   = (ushort*)(ws + 5u * (1u << 20));                 // 4 MB
    float*  q2      = (float*) (ws + 9u * (1u << 20));                 // 128 KB
    ushort* attn_bf = (ushort*)(ws + 9u * (1u << 20) + (128u << 10));  // 4 MB
    ushort* woutT   = (ushort*)(ws + 13u * (1u << 20) + (128u << 10)); // 64 KB

    k_embed<<<256, 256, 0, stream>>>(voxel, conv_w, conv_b, ln_g, ln_b, pos, emb);
    k_wt<<<8, 256, 0, stream>>>(wout, woutT);
    k_proj<<<NPAT / 16, 256, 0, stream>>>(emb, wqk, bqk, wv, bvv, qk_bf, vT_bf);
    k_q2<<<(NH * NPAT) / 256, 256, 0, stream>>>(qk_bf, q2);
    k_attn<<<NPAT / 64 * NH, 1024, 0, stream>>>(qk_bf, vT_bf, q2, alpha, attn_bf);
    k_out<<<NPAT / 16, 256, 0, stream>>>(attn_bf, woutT, bout, out);
}

// Round 11
// 202.135 us; speedup vs baseline: 2.1883x; 1.0087x over previous
//
#include <hip/hip_runtime.h>
#include <hip/hip_bf16.h>

// Problem constants
#define NPAT 4096   // patches
#define EDIM 64     // embedding per head
#define NH   8      // heads
#define HE   512    // H*E
#define OUTD 64     // CIN*P^3

typedef short bf16x8 __attribute__((ext_vector_type(8)));
typedef float f32x4  __attribute__((ext_vector_type(4)));
typedef unsigned short u16x4 __attribute__((ext_vector_type(4)));

#if __has_builtin(__builtin_amdgcn_exp2f)
#define EXP2(x) __builtin_amdgcn_exp2f(x)
#else
#define EXP2(x) exp2f(x)
#endif

__device__ __forceinline__ ushort f2bf(float f) {
    uint u = __builtin_bit_cast(uint, f);
    return (ushort)((u + 0x7FFFu + ((u >> 16) & 1u)) >> 16);
}
__device__ __forceinline__ float bf2f(ushort b) {
    return __builtin_bit_cast(float, ((uint)b) << 16);
}

// ---------------- Kernel 1 v3: conv3d(stride4)+LN+pos -> emb fp32 [4096][64]
// 1024 blocks (4 patches each; wave w = 1 patch, lane = e). Raises occupancy
// 1->4 waves/SIMD (support kernels were latency-bound at 1 block/CU).
__global__ __launch_bounds__(256) void k_embed(
    const float* __restrict__ voxel,   // [64][64][64]
    const float* __restrict__ conv_w,  // [64][64]
    const float* __restrict__ conv_b,  // [64]
    const float* __restrict__ ln_g, const float* __restrict__ ln_b,
    const float* __restrict__ pos,     // [4096][64]
    float* __restrict__ emb)           // [4096][64]
{
    const int b = blockIdx.x;            // d*64 + hh*4 + wq
    const int d = b >> 6, hh = (b >> 2) & 15, wq = b & 3;
    const int t = threadIdx.x;
    __shared__ float wsm[64][68];        // conv_w [e][m], stride 68: 16B-aligned rows
    __shared__ float vox[4][64];         // [patch p][m = i*16+j*4+k]

    for (int i = t; i < 4096; i += 256) wsm[i >> 6][i & 63] = conv_w[i];
    {
        const int pair = t >> 4;         // i*4+j
        const int q16  = t & 15;         // p*4+k
        const float v = voxel[(d * 4 + (pair >> 2)) * 4096 + (hh * 4 + (pair & 3)) * 64 +
                              wq * 16 + q16];
        vox[q16 >> 2][pair * 4 + (q16 & 3)] = v;
    }
    __syncthreads();

    const int p = t >> 6;                // wave = patch
    const int e = t & 63;                // lane = output channel
    const int n = d * 256 + hh * 16 + wq * 4 + p;

    float acc = conv_b[e];
    #pragma unroll
    for (int mi = 0; mi < 16; mi++) {
        const float4 vv = *(const float4*)&vox[p][mi * 4];
        const float4 ww = *(const float4*)&wsm[e][mi * 4];
        acc += vv.x * ww.x + vv.y * ww.y + vv.z * ww.z + vv.w * ww.w;
    }

    float s1 = acc, s2 = acc * acc;
    #pragma unroll
    for (int off = 1; off < 64; off <<= 1) {
        s1 += __shfl_xor(s1, off);
        s2 += __shfl_xor(s2, off);
    }
    const float mu  = s1 * (1.0f / 64.0f);
    const float var = s2 * (1.0f / 64.0f) - mu * mu;
    emb[n * 64 + e] = (acc - mu) * rsqrtf(var + 1e-5f) * ln_g[e] + ln_b[e] + pos[n * 64 + e];
}

// ---------------- Kernel 1b: woutT bf16 [64][512] (transpose+convert, tiny)
__global__ __launch_bounds__(256) void k_wt(
    const float* __restrict__ wout,  // [512][64]
    ushort* __restrict__ woutT)      // [64][512]
{
    const int b = blockIdx.x;        // 8 blocks, k-slab of 64
    const int t = threadIdx.x;
    __shared__ float ld[64][65];
    for (int i = t; i < 4096; i += 256) ld[i >> 6][i & 63] = wout[(b * 64 + (i >> 6)) * 64 + (i & 63)];
    __syncthreads();
    const int o = t >> 2, kb = (t & 3) * 16;
    #pragma unroll
    for (int j = 0; j < 16; j++)
        woutT[o * 512 + b * 64 + kb + j] = f2bf(ld[kb + j][o]);
}

// ---------------- Kernel 2 v3: projections + fused q2
// Grid (256, 8): block = 16 rows x head h -> 2048 blocks, 8 waves/SIMD.
// Thread = (e = lane, rg = wave); 4 rows each; q2 computed from the SAME
// bf16-rounded q via full-wave shuffle reduce (replaces k_q2 kernel).
__global__ __launch_bounds__(256) void k_proj(
    const float* __restrict__ emb,   // [4096][64]
    const float* __restrict__ wqk, const float* __restrict__ bqk,
    const float* __restrict__ wv,  const float* __restrict__ bvv,
    ushort* __restrict__ qk_bf,      // [H][4096][64]
    ushort* __restrict__ vT_bf,      // [H][64][4096]
    float* __restrict__ q2)          // [H][4096]
{
    const int n0 = blockIdx.x * 16;
    const int h  = blockIdx.y;
    const int t  = threadIdx.x;
    const int e  = t & 63, rg = t >> 6;
    __shared__ float es[16][64];
    for (int i = t; i < 1024; i += 256) es[i >> 6][i & 63] = emb[n0 * 64 + i];
    __syncthreads();

    const int he = h * 64 + e;
    const float bq = bqk[he], bv = bvv[he];
    float aq[4] = {bq, bq, bq, bq};
    float av[4] = {bv, bv, bv, bv};

    for (int ep = 0; ep < 64; ep++) {
        const float wq = wqk[ep * HE + he];
        const float wvv = wv[ep * HE + he];
        #pragma unroll
        for (int rr = 0; rr < 4; rr++) {
            const float x = es[rg * 4 + rr][ep];
            aq[rr] += x * wq;
            av[rr] += x * wvv;
        }
    }

    u16x4 vpk;
    #pragma unroll
    for (int rr = 0; rr < 4; rr++) {
        const int n = n0 + rg * 4 + rr;
        const ushort qb = f2bf(aq[rr]);
        qk_bf[((size_t)h * NPAT + n) * 64 + e] = qb;
        const float qf = bf2f(qb);
        float s = qf * qf;
        #pragma unroll
        for (int off = 1; off < 64; off <<= 1) s += __shfl_xor(s, off);
        if (e == 0) q2[h * NPAT + n] = s;
        vpk[rr] = f2bf(av[rr]);
    }
    *(u16x4*)&vT_bf[((size_t)h * 64 + e) * NPAT + n0 + rg * 4] = vpk;
}

// ---------------- Kernel 3: fused L2-distance attention, LDS-staged KV stream
// (byte-identical to R10's verified kernel)
__global__ __launch_bounds__(1024, 8) void k_attn(
    const ushort* __restrict__ qk,   // [H][N][64] bf16
    const ushort* __restrict__ vT,   // [H][64][N] bf16
    const float* __restrict__ q2,    // [H][N]
    const float* __restrict__ alpha, // [1]
    ushort* __restrict__ attn)       // [N][512] bf16
{
    const int bid = blockIdx.x;
    const int h  = bid & 7;
    const int bx = bid >> 3;
    const int tid = threadIdx.x;
    const int w  = tid >> 6;            // wave 0..15
    const int u  = w & 3;               // col-role (t-subtile for QK, c-tile for PV)
    const int rg = w >> 2;              // row group 0..3
    const int l  = tid & 63;
    const int lr = l & 15;
    const int lg = l >> 4;
    const float L2E = 1.4426950408889634f;
    const float ccl2e = alpha[0] * 0.125f * L2E;

    __shared__ ushort kv_lds[2][2][64 * 64]; // [buf][0=K,1=V][row*64+elem] 32 KB
    __shared__ ushort p_lds[4][16 * 64];     // per-rg P tile, XOR-swizzled (8 KB)
    __shared__ float  zpart[4][4][16];       // z stripe-sums [rg][u][row] (1 KB)

    const ushort* qkh = qk + (size_t)h * NPAT * 64;
    const ushort* vTh = vT + (size_t)h * 64 * NPAT;
    const float*  q2h = q2 + h * NPAT;

    const int row0 = bx * 64 + rg * 16;

    bf16x8 aq0, aq1;
    {
        const ushort* qrow = qkh + (size_t)(row0 + lr) * 64 + 8 * lg;
        aq0 = *(const bf16x8*)(qrow);
        aq1 = *(const bf16x8*)(qrow + 32);
    }
    float nq2[4];
    #pragma unroll
    for (int r = 0; r < 4; r++) nq2[r] = q2h[row0 + 4 * lg + r];

    const int w8   = w & 7;
    const int srow = w8 * 8 + (l >> 3);
    const int sch  = (l & 7) ^ (srow & 7);
    const ushort* ksrc0 = qkh + (size_t)srow * 64 + sch * 8;
    const ushort* vsrc0 = vTh + (size_t)srow * NPAT + sch * 8;
#define STAGE(bufi, it)                                                          \
    do {                                                                         \
        const ushort* _src = (w < 8) ? (ksrc0 + (size_t)(it) * 4096)             \
                                     : (vsrc0 + (size_t)(it) * 64);              \
        ushort* _dst = &kv_lds[bufi][w >> 3][w8 * 512];                          \
        __builtin_amdgcn_global_load_lds(                                        \
            (const __attribute__((address_space(1))) unsigned int*)_src,         \
            (__attribute__((address_space(3))) unsigned int*)_dst, 16, 0, 0);    \
    } while (0)

    f32x4 acc = (f32x4){0.f, 0.f, 0.f, 0.f};
    float zacc[4] = {0.f, 0.f, 0.f, 0.f};

    const int x7 = (lr & 7);
    char* prg = (char*)&p_lds[rg][0];

    STAGE(0, 0);
    float k2c = q2h[u * 16 + lr];

    for (int it = 0; it < 64; ++it) {
        const int buf = it & 1;
        __syncthreads();  // A: staging of buf complete, prev reads retired
        if (it + 1 < 64) STAGE(buf ^ 1, it + 1);
        float k2n = (it + 1 < 64) ? q2h[(it + 1) * 64 + u * 16 + lr] : 0.f;

        {
            const ushort* kb = &kv_lds[buf][0][0];
            const int krow = u * 16 + lr;
            bf16x8 bk0 = *(const bf16x8*)(kb + krow * 64 + ((lg ^ x7) << 3));
            bf16x8 bk1 = *(const bf16x8*)(kb + krow * 64 + (((lg + 4) ^ x7) << 3));
            f32x4 sc = (f32x4){0.f, 0.f, 0.f, 0.f};
            sc = __builtin_amdgcn_mfma_f32_16x16x32_bf16(aq0, bk0, sc, 0, 0, 0);
            sc = __builtin_amdgcn_mfma_f32_16x16x32_bf16(aq1, bk1, sc, 0, 0, 0);
            #pragma unroll
            for (int r = 0; r < 4; r++) {
                const float d = nq2[r] + k2c - 2.0f * sc[r];
                const float p = EXP2(ccl2e * EXP2(-L2E * d));
                zacc[r] += p;
                const int prow = 4 * lg + r, pcol = 16 * u + lr;
                const int byteoff = prow * 128 + ((pcol * 2) ^ ((prow & 7) << 4));
                *(ushort*)(prg + byteoff) = f2bf(p);
            }
        }
        asm volatile("s_waitcnt lgkmcnt(0)" ::: "memory");
        __builtin_amdgcn_s_barrier();

        {
            const ushort* vb = &kv_lds[buf][1][0];
            const int vrow = u * 16 + lr;
            bf16x8 bv0 = *(const bf16x8*)(vb + vrow * 64 + ((lg ^ x7) << 3));
            bf16x8 bv1 = *(const bf16x8*)(vb + vrow * 64 + (((lg + 4) ^ x7) << 3));
            char* rb = prg + lr * 128;
            const int xx = x7 << 4;
            bf16x8 pa0 = *(const bf16x8*)(rb + ((16 * lg) ^ xx));
            bf16x8 pa1 = *(const bf16x8*)(rb + ((64 + 16 * lg) ^ xx));
            acc = __builtin_amdgcn_mfma_f32_16x16x32_bf16(pa0, bv0, acc, 0, 0, 0);
            acc = __builtin_amdgcn_mfma_f32_16x16x32_bf16(pa1, bv1, acc, 0, 0, 0);
        }
        k2c = k2n;
    }
#undef STAGE

    #pragma unroll
    for (int r = 0; r < 4; r++) {
        float z = zacc[r];
        z += __shfl_xor(z, 1); z += __shfl_xor(z, 2);
        z += __shfl_xor(z, 4); z += __shfl_xor(z, 8);
        if (lr == 0) zpart[rg][u][4 * lg + r] = z;
    }
    __syncthreads();
    #pragma unroll
    for (int r = 0; r < 4; r++) {
        const int row = 4 * lg + r;
        const float zt = zpart[rg][0][row] + zpart[rg][1][row] +
                         zpart[rg][2][row] + zpart[rg][3][row];
        attn[(size_t)(row0 + row) * HE + h * 64 + u * 16 + lr] = f2bf(acc[r] / zt);
    }
}

// ---------------- Kernel 4 v3: out = attn_bf @ woutT^T + bout via MFMA
// 512 blocks of 8 rows (A-rows 8..15 duplicate rows 0..7, outputs discarded)
// -> 2 blocks/CU instead of 1.
__global__ __launch_bounds__(256) void k_out(
    const ushort* __restrict__ attn,  // [4096][512] bf16
    const ushort* __restrict__ woutT, // [64][512] bf16
    const float* __restrict__ bout,   // [64]
    float* __restrict__ out)          // [4096][64]
{
    const int n0 = blockIdx.x * 8;
    const int t = threadIdx.x;
    const int w = t >> 6, l = t & 63, lr = l & 15, lg = l >> 4;
    __shared__ ushort sa[8][520];     // +8 pad

    for (int c = t; c < 512; c += 256) {
        const int row = c >> 6, c8 = c & 63;
        *(bf16x8*)&sa[row][c8 * 8] = *(const bf16x8*)&attn[(size_t)(n0 + row) * 512 + c8 * 8];
    }
    __syncthreads();

    f32x4 acc = (f32x4){0.f, 0.f, 0.f, 0.f};
    const ushort* bp = woutT + (size_t)(w * 16 + lr) * 512 + 8 * lg;
    #pragma unroll
    for (int kk = 0; kk < 16; kk++) {
        bf16x8 a = *(const bf16x8*)&sa[lr & 7][kk * 32 + 8 * lg];
        bf16x8 bb = *(const bf16x8*)(bp + kk * 32);
        acc = __builtin_amdgcn_mfma_f32_16x16x32_bf16(a, bb, acc, 0, 0, 0);
    }
    if (lg < 2) {
        const float bo = bout[w * 16 + lr];
        #pragma unroll
        for (int r = 0; r < 4; r++)
            out[(size_t)(n0 + 4 * lg + r) * 64 + w * 16 + lr] = acc[r] + bo;
    }
}

extern "C" void kernel_launch(void* const* d_in, const int* in_sizes, int n_in,
                              void* d_out, int out_size, void* d_ws, size_t ws_size,
                              hipStream_t stream) {
    (void)in_sizes; (void)n_in; (void)out_size; (void)ws_size;
    const float* voxel  = (const float*)d_in[0];
    const float* conv_w = (const float*)d_in[1];
    const float* conv_b = (const float*)d_in[2];
    const float* ln_g   = (const float*)d_in[3];
    const float* ln_b   = (const float*)d_in[4];
    const float* pos    = (const float*)d_in[5];
    const float* wqk    = (const float*)d_in[6];
    const float* bqk    = (const float*)d_in[7];
    const float* wv     = (const float*)d_in[8];
    const float* bvv    = (const float*)d_in[9];
    const float* alpha  = (const float*)d_in[10];
    const float* wout   = (const float*)d_in[11];
    const float* bout   = (const float*)d_in[12];
    float* out = (float*)d_out;

    char* ws = (char*)d_ws;
    float*  emb     = (float*) (ws);                                   // 1 MB
    ushort* qk_bf   = (ushort*)(ws + (1u << 20));                      // 4 MB
    ushort* vT_bf   = (ushort*)(ws + 5u * (1u << 20));                 // 4 MB
    float*  q2      = (float*) (ws + 9u * (1u << 20));                 // 128 KB
    ushort* attn_bf = (ushort*)(ws + 9u * (1u << 20) + (128u << 10));  // 4 MB
    ushort* woutT   = (ushort*)(ws + 13u * (1u << 20) + (128u << 10)); // 64 KB

    k_embed<<<1024, 256, 0, stream>>>(voxel, conv_w, conv_b, ln_g, ln_b, pos, emb);
    k_wt<<<8, 256, 0, stream>>>(wout, woutT);
    k_proj<<<dim3(NPAT / 16, NH), 256, 0, stream>>>(emb, wqk, bqk, wv, bvv, qk_bf, vT_bf, q2);
    k_attn<<<NPAT / 64 * NH, 1024, 0, stream>>>(qk_bf, vT_bf, q2, alpha, attn_bf);
    k_out<<<NPAT / 8, 256, 0, stream>>>(attn_bf, woutT, bout, out);
}